// Round 4
// baseline (1519.912 us; speedup 1.0000x reference)
//
#include <hip/hip_runtime.h>
#include <hip/hip_bf16.h>

#define NROWS 20000
#define IPI 128
#define OPI 64
#define OPO 16

static __device__ __forceinline__ unsigned short f2bf(float f) {
    __hip_bfloat16 h = __float2bfloat16(f);           // RN
    return *reinterpret_cast<unsigned short*>(&h);
}

// ---------------- kernel 0: B = X @ W1  [N,128]x[128,64] ----------------
__global__ __launch_bounds__(256)
void k_xw1(const float* __restrict__ X, const float* __restrict__ W1,
           float* __restrict__ B) {
    __shared__ float w1[IPI * OPI];           // 32 KB
    const int t = threadIdx.x;
    for (int i = t * 4; i < IPI * OPI; i += 1024)
        *(float4*)&w1[i] = *(const float4*)&W1[i];
    __syncthreads();

    const int r  = blockIdx.x * 16 + (t >> 4);
    const int c4 = (t & 15) * 4;
    if (r >= NROWS) return;
    const float* xr = X + (size_t)r * IPI;
    float4 acc = make_float4(0.f, 0.f, 0.f, 0.f);
    #pragma unroll 8
    for (int k = 0; k < IPI; ++k) {
        const float x = xr[k];
        const float4 w = *(const float4*)&w1[k * OPI + c4];
        acc.x = fmaf(x, w.x, acc.x);
        acc.y = fmaf(x, w.y, acc.y);
        acc.z = fmaf(x, w.z, acc.z);
        acc.w = fmaf(x, w.w, acc.w);
    }
    *(float4*)&B[(size_t)r * OPI + c4] = acc;
}

// -------- k_gemm1: H[s] = A[:,kb:ke] @ B[kb:ke,:]; also emits bf16(A) ---
// 256 threads, tile = 128 rows x 64 cols, 8x4 acc per thread
__global__ __launch_bounds__(256)
void k_gemm1(const float* __restrict__ A, const float* __restrict__ Bm,
             float* __restrict__ Out, __hip_bfloat16* __restrict__ Abf,
             int KC, int writeAbf) {
    __shared__ float lds_a[64 * 132];         // [k][row0..127], stride 132 (16B-aligned)
    __shared__ float lds_b[64 * 64];          // [k][col]
    const int t  = threadIdx.x;
    const int tr = t & 15;                    // rows tr*8 .. tr*8+7
    const int tc = t >> 4;                    // cols tc*4 .. +3
    const int brow    = blockIdx.x * 128;
    const int k_begin = blockIdx.y * KC;
    const int k_end   = min(NROWS, k_begin + KC);

    float acc[8][4];
    #pragma unroll
    for (int i = 0; i < 8; ++i)
        #pragma unroll
        for (int j = 0; j < 4; ++j) acc[i][j] = 0.f;

    const int cl = (t & 15) * 4;              // staging: k offset within tile
    const int rl = t >> 4;                    // staging: row offset base (0..15)

    for (int kt = k_begin; kt < k_end; kt += 64) {
        // stage A tile [128 rows][64 k] -> transposed lds_a[k][row]; emit bf16 copy
        #pragma unroll
        for (int rr = 0; rr < 128; rr += 16) {
            const int row = brow + rl + rr;
            const int kg  = kt + cl;          // kg mult of 4; k_end mult of 4
            float4 v = make_float4(0.f, 0.f, 0.f, 0.f);
            const bool ok = (row < NROWS) && (kg < k_end);
            if (ok) v = *(const float4*)&A[(size_t)row * NROWS + kg];
            lds_a[(cl + 0) * 132 + rl + rr] = v.x;
            lds_a[(cl + 1) * 132 + rl + rr] = v.y;
            lds_a[(cl + 2) * 132 + rl + rr] = v.z;
            lds_a[(cl + 3) * 132 + rl + rr] = v.w;
            if (writeAbf && ok) {
                ushort4 p;
                p.x = f2bf(v.x); p.y = f2bf(v.y); p.z = f2bf(v.z); p.w = f2bf(v.w);
                *(ushort4*)&Abf[(size_t)row * NROWS + kg] = p;
            }
        }
        // stage B tile: rows kt..kt+63 x 64 cols (contiguous)
        #pragma unroll
        for (int i = t * 4; i < 64 * 64; i += 1024) {
            const int kg = kt + (i >> 6);
            float4 v = make_float4(0.f, 0.f, 0.f, 0.f);
            if (kg < k_end) v = *(const float4*)&Bm[(size_t)kt * OPI + i];
            *(float4*)&lds_b[i] = v;
        }
        __syncthreads();

        #pragma unroll 4
        for (int k = 0; k < 64; ++k) {
            float a8[8];
            *(float4*)&a8[0] = *(const float4*)&lds_a[k * 132 + tr * 8];
            *(float4*)&a8[4] = *(const float4*)&lds_a[k * 132 + tr * 8 + 4];
            const float4 bv = *(const float4*)&lds_b[k * 64 + tc * 4];
            const float b4[4] = {bv.x, bv.y, bv.z, bv.w};
            #pragma unroll
            for (int i = 0; i < 8; ++i)
                #pragma unroll
                for (int j = 0; j < 4; ++j)
                    acc[i][j] = fmaf(a8[i], b4[j], acc[i][j]);
        }
        __syncthreads();
    }

    float* outp = Out + (size_t)blockIdx.y * NROWS * OPI;
    #pragma unroll
    for (int i = 0; i < 8; ++i) {
        const int row = brow + tr * 8 + i;
        if (row < NROWS)
            *(float4*)&outp[(size_t)row * OPI + tc * 4] =
                make_float4(acc[i][0], acc[i][1], acc[i][2], acc[i][3]);
    }
}

// ------------- k_hw2: Z = relu(sum_s Hpart[s]) @ W2  [N,64]x[64,16] -----
__global__ __launch_bounds__(256)
void k_hw2(const float* __restrict__ Hpart, const float* __restrict__ W2,
           float* __restrict__ Z, int S1) {
    __shared__ float w2[OPI * OPO];           // 4 KB
    __shared__ float hs[16 * 68];
    const int t = threadIdx.x;
    if (t * 4 < OPI * OPO)
        *(float4*)&w2[t * 4] = *(const float4*)&W2[t * 4];

    const int r  = t >> 4;
    const int c4 = (t & 15) * 4;
    const size_t rowg = (size_t)blockIdx.x * 16 + r;   // 1250*16 == 20000 exact

    float4 h = make_float4(0.f, 0.f, 0.f, 0.f);
    for (int s = 0; s < S1; ++s) {
        const float4 v = *(const float4*)&Hpart[((size_t)s * NROWS + rowg) * OPI + c4];
        h.x += v.x; h.y += v.y; h.z += v.z; h.w += v.w;
    }
    hs[r * 68 + c4 + 0] = fmaxf(h.x, 0.f);
    hs[r * 68 + c4 + 1] = fmaxf(h.y, 0.f);
    hs[r * 68 + c4 + 2] = fmaxf(h.z, 0.f);
    hs[r * 68 + c4 + 3] = fmaxf(h.w, 0.f);
    __syncthreads();

    const int c = t & 15;
    float z = 0.f;
    #pragma unroll 8
    for (int k = 0; k < OPI; ++k)
        z = fmaf(hs[r * 68 + k], w2[k * OPO + c], z);
    Z[rowg * OPO + c] = z;
}

// -------- k_gemm2<ABF>: L[s] = A[:,kb:ke] @ Z[kb:ke,:]  (A bf16 or f32) --
// 256 threads, tile = 64 rows x 16 cols, 4x1 acc per thread
template<bool ABF>
__global__ __launch_bounds__(256)
void k_gemm2(const float* __restrict__ Af, const __hip_bfloat16* __restrict__ Ab,
             const float* __restrict__ Zm, float* __restrict__ Out, int KC) {
    __shared__ float lds_a[64 * 68];          // [k][row], stride 68
    __shared__ float lds_b[64 * OPO];         // [k][col]
    const int t  = threadIdx.x;
    const int tr = t & 15;                    // rows tr*4 .. +3
    const int tc = t >> 4;                    // col tc
    const int brow    = blockIdx.x * 64;
    const int k_begin = blockIdx.y * KC;
    const int k_end   = min(NROWS, k_begin + KC);

    float acc[4] = {0.f, 0.f, 0.f, 0.f};

    const int cl = (t & 15) * 4;
    const int rl = t >> 4;

    for (int kt = k_begin; kt < k_end; kt += 64) {
        #pragma unroll
        for (int rr = 0; rr < 64; rr += 16) {
            const int row = brow + rl + rr;
            const int kg  = kt + cl;
            float4 v = make_float4(0.f, 0.f, 0.f, 0.f);
            if (row < NROWS && kg < k_end) {
                if constexpr (ABF) {
                    const ushort4 u = *(const ushort4*)&Ab[(size_t)row * NROWS + kg];
                    v.x = __uint_as_float((unsigned)u.x << 16);
                    v.y = __uint_as_float((unsigned)u.y << 16);
                    v.z = __uint_as_float((unsigned)u.z << 16);
                    v.w = __uint_as_float((unsigned)u.w << 16);
                } else {
                    v = *(const float4*)&Af[(size_t)row * NROWS + kg];
                }
            }
            lds_a[(cl + 0) * 68 + rl + rr] = v.x;
            lds_a[(cl + 1) * 68 + rl + rr] = v.y;
            lds_a[(cl + 2) * 68 + rl + rr] = v.z;
            lds_a[(cl + 3) * 68 + rl + rr] = v.w;
        }
        {   // stage Z tile: 64 x 16 = 1024 floats, one float4 per thread
            const int i  = t * 4;
            const int kg = kt + (i >> 4);
            float4 v = make_float4(0.f, 0.f, 0.f, 0.f);
            if (kg < k_end) v = *(const float4*)&Zm[(size_t)kt * OPO + i];
            *(float4*)&lds_b[i] = v;
        }
        __syncthreads();

        #pragma unroll 8
        for (int k = 0; k < 64; ++k) {
            const float4 av = *(const float4*)&lds_a[k * 68 + tr * 4];
            const float bz = lds_b[k * OPO + tc];
            acc[0] = fmaf(av.x, bz, acc[0]);
            acc[1] = fmaf(av.y, bz, acc[1]);
            acc[2] = fmaf(av.z, bz, acc[2]);
            acc[3] = fmaf(av.w, bz, acc[3]);
        }
        __syncthreads();
    }

    float* outp = Out + (size_t)blockIdx.y * NROWS * OPO;
    #pragma unroll
    for (int i = 0; i < 4; ++i) {
        const int row = brow + tr * 4 + i;
        if (row < NROWS) outp[(size_t)row * OPO + tc] = acc[i];
    }
}

// ------------- k_softmax: out = softmax(sum_s Lpart[s], axis=1) ---------
__global__ __launch_bounds__(256)
void k_softmax(const float* __restrict__ Lpart, float* __restrict__ out, int S2) {
    const int t = threadIdx.x;
    const size_t base = (size_t)blockIdx.x * 256;      // 16 rows x 16 cols
    float v = 0.f;
    for (int s = 0; s < S2; ++s)
        v += Lpart[(size_t)s * NROWS * OPO + base + t];
    float m = v;
    #pragma unroll
    for (int d = 8; d >= 1; d >>= 1) m = fmaxf(m, __shfl_xor(m, d, 16));
    const float e = expf(v - m);
    float sum = e;
    #pragma unroll
    for (int d = 8; d >= 1; d >>= 1) sum += __shfl_xor(sum, d, 16);
    out[base + t] = e / sum;
}

// ------------------------------------------------------------------------
extern "C" void kernel_launch(void* const* d_in, const int* in_sizes, int n_in,
                              void* d_out, int out_size, void* d_ws, size_t ws_size,
                              hipStream_t stream) {
    const float* A  = (const float*)d_in[0];
    const float* X  = (const float*)d_in[1];
    const float* W1 = (const float*)d_in[2];
    const float* W2 = (const float*)d_in[3];
    float* out = (float*)d_out;

    auto fneed = [](int s1, int s2) -> size_t {
        return ((size_t)NROWS * OPI + (size_t)NROWS * OPO +
                (size_t)s1 * NROWS * OPI + (size_t)s2 * NROWS * OPO) * sizeof(float);
    };
    const size_t abf_bytes = (size_t)NROWS * NROWS * sizeof(__hip_bfloat16);

    int S1 = 16, S2 = 8;
    bool use_abf = (fneed(S1, S2) + abf_bytes) <= ws_size;
    while ((S1 > 1 || S2 > 1) &&
           fneed(S1, S2) + (use_abf ? abf_bytes : 0) > ws_size) {
        if (S1 > 1) S1 >>= 1;
        if (S2 > 1) S2 >>= 1;
    }

    char* p = (char*)d_ws;
    __hip_bfloat16* Abf = use_abf ? (__hip_bfloat16*)p : nullptr;
    float* fbase = (float*)(p + (use_abf ? abf_bytes : 0));
    float* B = fbase;                           // [N][64]
    float* Z = B + (size_t)NROWS * OPI;         // [N][16]
    float* H = Z + (size_t)NROWS * OPO;         // [S1][N][64]
    float* L = H + (size_t)S1 * NROWS * OPI;    // [S2][N][16]

    const int MT1 = (NROWS + 127) / 128;        // 157
    const int MT2 = (NROWS + 63) / 64;          // 313
    const int KC1 = ((((NROWS + S1 - 1) / S1) + 63) & ~63);
    const int KC2 = ((((NROWS + S2 - 1) / S2) + 63) & ~63);

    k_xw1<<<dim3((NROWS + 15) / 16), 256, 0, stream>>>(X, W1, B);
    k_gemm1<<<dim3(MT1, S1), 256, 0, stream>>>(A, B, H, Abf, KC1, use_abf ? 1 : 0);
    k_hw2<<<dim3(NROWS / 16), 256, 0, stream>>>(H, W2, Z, S1);
    if (use_abf)
        k_gemm2<true><<<dim3(MT2, S2), 256, 0, stream>>>(A, Abf, Z, L, KC2);
    else
        k_gemm2<false><<<dim3(MT2, S2), 256, 0, stream>>>(A, Abf, Z, L, KC2);
    k_softmax<<<dim3(NROWS * OPO / 256), 256, 0, stream>>>(L, out, S2);
}